// Round 7
// baseline (336.946 us; speedup 1.0000x reference)
//
#include <hip/hip_runtime.h>
#include <hip/hip_bf16.h>

// Problem constants (match reference)
#define NN 100000   // nodes
#define NE 400000   // edges per etype
#define NT 3        // etypes
#define NL 3        // layers
#define DD 64       // feature dim
#define M_TOT (NT * NN)             // 300000 concatenated (etype,node) rows
#define RPB 2048                    // rows per pair-bucket (row >> 11)
#define NBKT ((M_TOT + RPB - 1) / RPB)   // 147 buckets
#define P3CAP 32                    // LDS pairs per bucket in pair_scatter
#define P3GRID 256                  // pair_scatter grid
#define PCAP 13312                  // fixed pair capacity per bucket
                                    //   (mean 8163 + block-drain slack 4096 + >5 sigma)
#define CSR_THREADS 1024            // bucket_csr block size (round-18)
#define COLCAP_BKT 9216             // fixed col capacity per 2048-row bucket
                                    //   (mean 8163 + ~11.7 sigma)
#define OVF_CAP 500000              // ovf region capacity (uint2 entries)
#define GGRID 2048                  // persistent gather grid (round-19)

// Data established as fp32 (round-3 runtime dtype detection).
// Round-6: never fuse the random gather into the LDS-heavy GEMM (occupancy).
// Round-8: scattered 4B stores amplify ~16x at HBM -> line-grouped writes.
// Round-9: pair capacity must include per-block sentinel padding.
// Round-11: chunked pair_scatter overflows P3CAP; keep 256-edge rounds.
// Round-12/13: gather -> 8 rows/wave (ds_swizzle col broadcast, literal
// pattern): 79->46us, VALUBusy 70->22%, fetch path 2.4->3.85 TB/s. Verified.
// Round-14: gather loops to per-GROUP degree (exec-masked divergence).
// Round-15/16 LESSON (measured twice): B fragments MUST come from LDS;
// B-from-global inside the MFMA loop = latency-bound 53-56us.
// Round-17 LESSON: reg-prefetch pipeline in the LDS gemm REGRESSED (+8us/
// dispatch): extra VGPR state + loop-head waitcnts beat the compiler's own
// schedule. Keep the simple barrier structure.
// Round-18: bucket_csr -> ONE 1024-thread block/bucket (saved ~15us).
// Round-19 (this): (a) layer_gemm tile 64->128 rows/block (2 m-tiles/wave,
// B-frag reuse, barriers per output row halved; LDS 52KB -> 3 blocks/CU);
// (b) gather persistent 2048-block grid-stride (concurrency probe: if dur
// unchanged at higher occupancy, the random-128B txn path is saturated).

typedef __attribute__((ext_vector_type(8))) short bf16x8;  // 8 bf16 (4 VGPRs)
typedef __attribute__((ext_vector_type(4))) float f32x4;

static __device__ __forceinline__ unsigned short f2b(float f) {
    __hip_bfloat16 b = __float2bfloat16(f);
    return *reinterpret_cast<unsigned short*>(&b);
}
static __device__ __forceinline__ float b2f(unsigned short u) {
    __hip_bfloat16 b = *reinterpret_cast<__hip_bfloat16*>(&u);
    return __bfloat162float(b);
}

// ---- init: fixed-capacity cursors (replaces count+scan+memset+memcpy) ------
__global__ void init_kernel(int* __restrict__ gcur, int* __restrict__ ocnt) {
    int i = threadIdx.x;
    if (i < NBKT) gcur[i] = i * PCAP;
    if (i == 0) ocnt[0] = 0;
}

// ---- pair scatter: packed pairs into fixed bucket regions (r10-proven) -----
// pair = (row_local<<17)|src. Global writes only as aligned 64B groups of 16;
// drain pads with sentinel 0xFFFFFFFF (src field >= NN). 256-edge rounds.
__global__ __launch_bounds__(256) void pair_scatter(
    const int* __restrict__ src, const int* __restrict__ dst,
    int* __restrict__ gcur, unsigned* __restrict__ pairs,
    uint2* __restrict__ ovf, int* __restrict__ ocnt) {
    __shared__ unsigned buf[NBKT][P3CAP];   // 18.8 KB
    __shared__ int fill[NBKT];
    for (int i = threadIdx.x; i < NBKT; i += 256) fill[i] = 0;
    __syncthreads();
    const int total = NT * NE;
    int per = (total + gridDim.x - 1) / gridDim.x;
    int beg = blockIdx.x * per;
    int fin = beg + per; if (fin > total) fin = total;
    for (int bse = beg; bse < fin; bse += 256) {
        int e = bse + threadIdx.x;
        if (e < fin) {
            int t = e / NE;
            int row = t * NN + dst[e];
            int bk = row >> 11;
            unsigned pr = ((unsigned)(row & 2047) << 17) | (unsigned)src[e];
            int pos = atomicAdd(&fill[bk], 1);
            if (pos < P3CAP) buf[bk][pos] = pr;
            else {
                int o = atomicAdd(ocnt, 1);
                if (o < OVF_CAP) ovf[o] = make_uint2((unsigned)src[e], (unsigned)row);
            }
        }
        __syncthreads();
        for (int bk = threadIdx.x; bk < NBKT; bk += 256) {
            int n = fill[bk]; if (n > P3CAP) n = P3CAP;
            int g = n >> 4;
            if (g) {
                int gb = atomicAdd(&gcur[bk], g * 16);
#pragma unroll
                for (int q = 0; q < 4; ++q)
                    *(int4*)&pairs[gb + q * 4] = *(const int4*)&buf[bk][q * 4];
                if (g == 2)
#pragma unroll
                    for (int q = 0; q < 4; ++q)
                        *(int4*)&pairs[gb + 16 + q * 4] =
                            *(const int4*)&buf[bk][16 + q * 4];
                int rem = n - g * 16;
                for (int k = 0; k < rem; ++k) buf[bk][k] = buf[bk][g * 16 + k];
                fill[bk] = rem;
            } else fill[bk] = n;
        }
        __syncthreads();
    }
    // drain: pad to 16 with sentinels to keep gcur 64B-aligned
    for (int bk = threadIdx.x; bk < NBKT; bk += 256) {
        int n = fill[bk]; if (n > P3CAP) n = P3CAP;
        if (n) {
            int m = (n + 15) & ~15;
            for (int k = n; k < m; ++k) buf[bk][k] = 0xFFFFFFFFu;
            int gb = atomicAdd(&gcur[bk], m);
            for (int grp = 0; grp < m >> 4; ++grp)
#pragma unroll
                for (int q = 0; q < 4; ++q)
                    *(int4*)&pairs[gb + grp * 16 + q * 4] =
                        *(const int4*)&buf[bk][grp * 16 + q * 4];
        }
    }
}

// ---- CSR finalize: ONE 1024-thread block per bucket (round-18) -------------
__global__ __launch_bounds__(CSR_THREADS) void bucket_csr(
    const int* __restrict__ gcur, const unsigned* __restrict__ pairs,
    const uint2* __restrict__ ovf, const int* __restrict__ ocnt,
    int* __restrict__ rs, int* __restrict__ rse, int* __restrict__ col) {
    __shared__ int cnt_s[RPB];
    __shared__ int cur_s[RPB];
    __shared__ int part[CSR_THREADS];
    const int bk = blockIdx.x;              // 0 .. NBKT-1
    const int row0 = bk * RPB;              // global row base
    const int nrows = (M_TOT - row0 < RPB) ? (M_TOT - row0) : RPB;
    for (int i = threadIdx.x; i < RPB; i += CSR_THREADS) cnt_s[i] = 0;
    __syncthreads();
    const int pb = bk * PCAP, pe = gcur[bk];
    for (int p = pb + threadIdx.x; p < pe; p += CSR_THREADS) {
        unsigned pr = pairs[p];
        if ((pr & 0x1FFFFu) < NN)
            atomicAdd(&cnt_s[pr >> 17], 1);   // rl < RPB by construction
    }
    int no = ocnt[0]; if (no > OVF_CAP) no = OVF_CAP;
    for (int o = threadIdx.x; o < no; o += CSR_THREADS) {
        int rl = (int)ovf[o].y - row0;
        if (rl >= 0 && rl < nrows) atomicAdd(&cnt_s[rl], 1);
    }
    __syncthreads();
    // exclusive scan of 2048 counts (2 per thread)
    int t0 = threadIdx.x * 2, sum = 0;
    int exl[2];
#pragma unroll
    for (int k = 0; k < 2; ++k) { exl[k] = sum; sum += cnt_s[t0 + k]; }
    part[threadIdx.x] = sum;
    __syncthreads();
    for (int o = 1; o < CSR_THREADS; o <<= 1) {
        int v = (threadIdx.x >= o) ? part[threadIdx.x - o] : 0;
        __syncthreads();
        part[threadIdx.x] += v;
        __syncthreads();
    }
    int off = part[threadIdx.x] - sum + bk * COLCAP_BKT;
#pragma unroll
    for (int k = 0; k < 2; ++k) {
        int idx = t0 + k;
        int ex = exl[k] + off;
        cur_s[idx] = ex;
        if (idx < nrows) { rs[row0 + idx] = ex; rse[row0 + idx] = ex + cnt_s[idx]; }
    }
    __syncthreads();
    for (int p = pb + threadIdx.x; p < pe; p += CSR_THREADS) {
        unsigned pr = pairs[p];
        unsigned s = pr & 0x1FFFFu;
        if (s < NN) {
            int pos = atomicAdd(&cur_s[pr >> 17], 1);
            col[pos] = (int)s;
        }
    }
    for (int o = threadIdx.x; o < no; o += CSR_THREADS) {
        int rl = (int)ovf[o].y - row0;
        if (rl >= 0 && rl < nrows) {
            int pos = atomicAdd(&cur_s[rl], 1);
            col[pos] = (int)ovf[o].x;
        }
    }
}

// ---- one-time weight transpose: Wt[lt][j][k] = bf16(W'[k][j]), K=128 -------
__global__ __launch_bounds__(256) void wtrans_kernel(
    const float* __restrict__ Ws, const float* __restrict__ Wn,
    unsigned short* __restrict__ Wt) {
    int lt = blockIdx.x;   // 0..8
    for (int p = threadIdx.x; p < DD * 2 * DD; p += 256) {
        int j = p >> 7, k = p & 127;
        float v = (k < DD) ? Ws[(size_t)lt * DD * DD + k * DD + j]
                           : Wn[(size_t)lt * DD * DD + (k - DD) * DD + j];
        Wt[(size_t)lt * 8192 + j * 128 + k] = f2b(v);
    }
}

// ---- aggregation: pull-mode mean gather, 8 rows/wave, persistent grid ------
template <int HBF>
__global__ __launch_bounds__(256) void gather_kernel(
    const void* __restrict__ hv, const int* __restrict__ rs,
    const int* __restrict__ rse, const int* __restrict__ col,
    unsigned short* __restrict__ meanb) {
    const int lane = threadIdx.x & 63;
    const int g = lane >> 3;       // row group within wave (0..7)
    const int fc = lane & 7;       // feature chunk (8 feats x 16B)
    const unsigned short* hb = (const unsigned short*)hv;
    const float* hf = (const float*)hv;
    const int ntiles = (M_TOT + 31) / 32;   // 32 rows per block-tile
    for (int tile = blockIdx.x; tile < ntiles; tile += gridDim.x) {
        const int i = (tile * 4 + (threadIdx.x >> 6)) * 8 + g;
        const bool live = i < M_TOT;
        const int start = live ? rs[i] : 0;
        const int end   = live ? rse[i] : 0;
        const int deg = end - start;   // uniform within the 8-lane group
        float acc[8];
#pragma unroll
        for (int j = 0; j < 8; ++j) acc[j] = 0.f;
        for (int base = 0; base < deg; base += 8) {
            int e = start + base + fc;
            int cl = col[(e < end) ? e : start];   // 8 contiguous cols per group

#define GSTEP(K)                                                               \
            {                                                                  \
                int idx = __builtin_amdgcn_ds_swizzle(cl, ((K) << 5) | 24);    \
                bool v = (base + (K)) < deg;                                   \
                float mk = v ? 1.f : 0.f;                                      \
                int ix = v ? idx : 0;                                          \
                if (HBF) {                                                     \
                    int4 rv = *(const int4*)&hb[(size_t)ix * DD + fc * 8];     \
                    const unsigned* wp = (const unsigned*)&rv;                 \
                    _Pragma("unroll")                                          \
                    for (int j = 0; j < 4; ++j) {                              \
                        unsigned w = wp[j];                                    \
                        float lo = __uint_as_float(w << 16);                   \
                        float hi = __uint_as_float(w & 0xffff0000u);           \
                        acc[2 * j]     = fmaf(lo, mk, acc[2 * j]);             \
                        acc[2 * j + 1] = fmaf(hi, mk, acc[2 * j + 1]);         \
                    }                                                          \
                } else {                                                       \
                    float4 a = *(const float4*)&hf[(size_t)ix * DD + fc * 8];  \
                    float4 b = *(const float4*)&hf[(size_t)ix * DD + fc * 8 + 4];\
                    acc[0] = fmaf(a.x, mk, acc[0]);                            \
                    acc[1] = fmaf(a.y, mk, acc[1]);                            \
                    acc[2] = fmaf(a.z, mk, acc[2]);                            \
                    acc[3] = fmaf(a.w, mk, acc[3]);                            \
                    acc[4] = fmaf(b.x, mk, acc[4]);                            \
                    acc[5] = fmaf(b.y, mk, acc[5]);                            \
                    acc[6] = fmaf(b.z, mk, acc[6]);                            \
                    acc[7] = fmaf(b.w, mk, acc[7]);                            \
                }                                                              \
            }
            GSTEP(0) GSTEP(1) GSTEP(2) GSTEP(3)
            GSTEP(4) GSTEP(5) GSTEP(6) GSTEP(7)
#undef GSTEP
        }
        float sc = (deg > 0) ? 1.f / (float)deg : 0.f;
        unsigned ow[4];
#pragma unroll
        for (int j = 0; j < 4; ++j) {
            unsigned lo = f2b(acc[2 * j] * sc);
            unsigned hi = f2b(acc[2 * j + 1] * sc);
            ow[j] = lo | (hi << 16);
        }
        if (live)
            *(int4*)&meanb[(size_t)i * DD + fc * 8] = *(const int4*)ow;
    }
}

// ---- per-layer fused MFMA GEMM, 128 rows/block (round-19) ------------------
// r2-proven barrier structure; each wave owns TWO 16-row m-tiles, B-frag
// reused across both. LDS 52KB -> 3 blocks/CU. Barriers per output row /2.
template <int HBF, int OBF>
__global__ __launch_bounds__(256) void layer_gemm(
    const void* __restrict__ hv, const unsigned short* __restrict__ meanb,
    const unsigned short* __restrict__ Wt, const float* __restrict__ bias,
    void* __restrict__ outv, int relu) {
    __shared__ __align__(16) short A_s[128 * 136]; // [row][k]: k<64 h, k>=64 mean
    __shared__ __align__(16) short B_s[64 * 136];  // [col j][k]

    const int tx = threadIdx.x;
    const int n0 = blockIdx.x * 128;
    const int lane = tx & 63, w = tx >> 6;
    const int q = lane >> 4, m16 = lane & 15;
    const int rr = tx >> 4;
    const int k0 = (tx & 15) * 4;
    const int bj = tx >> 2;
    const int bk = (tx & 3) * 32;

#pragma unroll
    for (int qq = 0; qq < 8; ++qq) {
        int r = rr + 16 * qq;
        int n = n0 + r;
        ushort4 hb4 = make_ushort4(0, 0, 0, 0);
        if (n < NN) {
            if (HBF) {
                hb4 = *(const ushort4*)&((const unsigned short*)hv)[(size_t)n * DD + k0];
            } else {
                float4 hf = *(const float4*)&((const float*)hv)[(size_t)n * DD + k0];
                hb4 = make_ushort4(f2b(hf.x), f2b(hf.y), f2b(hf.z), f2b(hf.w));
            }
        }
        *(ushort4*)&A_s[r * 136 + k0] = hb4;
    }

    float acc_sum[2][4][4];
#pragma unroll
    for (int mt = 0; mt < 2; ++mt)
#pragma unroll
        for (int c = 0; c < 4; ++c)
#pragma unroll
            for (int r = 0; r < 4; ++r) acc_sum[mt][c][r] = 0.f;

    for (int t = 0; t < NT; ++t) {
#pragma unroll
        for (int qq = 0; qq < 8; ++qq) {
            int r = rr + 16 * qq;
            int n = n0 + r;
            ushort4 mv = make_ushort4(0, 0, 0, 0);
            if (n < NN)
                mv = *(const ushort4*)&meanb[((size_t)t * NN + n) * DD + k0];
            *(ushort4*)&A_s[r * 136 + 64 + k0] = mv;
        }
        {
            const unsigned short* wt = Wt + (size_t)t * 8192 + bj * 128 + bk;
#pragma unroll
            for (int u = 0; u < 4; ++u)
                *(int4*)&B_s[bj * 136 + bk + u * 8] = *(const int4*)&wt[u * 8];
        }
        __syncthreads();

        f32x4 acc[2][4];
#pragma unroll
        for (int mt = 0; mt < 2; ++mt)
#pragma unroll
            for (int c = 0; c < 4; ++c) acc[mt][c] = (f32x4){0.f, 0.f, 0.f, 0.f};
#pragma unroll
        for (int kt = 0; kt < 4; ++kt) {
            bf16x8 a0 = *(const bf16x8*)&A_s[(32 * w + m16) * 136 + kt * 32 + q * 8];
            bf16x8 a1 = *(const bf16x8*)&A_s[(32 * w + 16 + m16) * 136 + kt * 32 + q * 8];
#pragma unroll
            for (int c = 0; c < 4; ++c) {
                bf16x8 b = *(const bf16x8*)&B_s[(c * 16 + m16) * 136 + kt * 32 + q * 8];
                acc[0][c] = __builtin_amdgcn_mfma_f32_16x16x32_bf16(a0, b, acc[0][c], 0, 0, 0);
                acc[1][c] = __builtin_amdgcn_mfma_f32_16x16x32_bf16(a1, b, acc[1][c], 0, 0, 0);
            }
        }

#pragma unroll
        for (int c = 0; c < 4; ++c) {
            float bv = bias[t * DD + c * 16 + m16];
#pragma unroll
            for (int mt = 0; mt < 2; ++mt)
#pragma unroll
                for (int r = 0; r < 4; ++r) {
                    float v = acc[mt][c][r] + bv;
                    if (relu) v = fmaxf(v, 0.f);
                    acc_sum[mt][c][r] += v;
                }
        }
        __syncthreads();
    }

#pragma unroll
    for (int mt = 0; mt < 2; ++mt)
#pragma unroll
        for (int c = 0; c < 4; ++c)
#pragma unroll
            for (int r = 0; r < 4; ++r) {
                int n = n0 + 32 * w + 16 * mt + q * 4 + r;
                if (n >= NN) continue;
                size_t idx = (size_t)n * DD + c * 16 + m16;
                if (OBF)
                    ((unsigned short*)outv)[idx] = f2b(acc_sum[mt][c][r]);
                else
                    ((float*)outv)[idx] = acc_sum[mt][c][r];
            }
}

extern "C" void kernel_launch(void* const* d_in, const int* in_sizes, int n_in,
                              void* d_out, int out_size, void* d_ws, size_t ws_size,
                              hipStream_t stream) {
    const float* feat    = (const float*)d_in[0];
    const float* W_self  = (const float*)d_in[1];
    const float* W_neigh = (const float*)d_in[2];
    const float* bias    = (const float*)d_in[3];
    const int* src = (const int*)d_in[4];
    const int* dst = (const int*)d_in[5];

    // ws layout (byte offsets; total 59.18 MB <= proven 59.6 MB):
    //   gcur @0 (1 KB) | ocnt @1024 | rs @8192 (1.2 MB) | rse @1,208,320
    //   col @2,408,448 (5.42 MB: 147 x 9216 ints)
    //   Wt  @7,827,584 (147,456 B)
    //   X2  @7,975,040 (12.8 MB bf16)
    //   meanb @20,775,040 (38.4 MB bf16)
    //   pairs = alias of meanb (7.83 MB: 147 x 13312, dead after bucket_csr)
    //   ovf   = meanb + 8,388,608 (4 MB, dead after bucket_csr)
    char* ws = (char*)d_ws;
    int* gcur  = (int*)(ws + 0);
    int* ocnt  = (int*)(ws + 1024);
    int* rs    = (int*)(ws + 8192);
    int* rse   = (int*)(ws + 1208320);
    int* col   = (int*)(ws + 2408448);
    unsigned short* Wt    = (unsigned short*)(ws + 7827584);
    unsigned short* X2    = (unsigned short*)(ws + 7975040);
    unsigned short* meanb = (unsigned short*)(ws + 20775040);
    unsigned*       pairs = (unsigned*)(ws + 20775040);
    uint2*          ovf   = (uint2*)(ws + 20775040 + 8388608);

    // ---- CSR build: fixed-capacity buckets, no count/scan pass ----
    init_kernel<<<1, 256, 0, stream>>>(gcur, ocnt);
    pair_scatter<<<P3GRID, 256, 0, stream>>>(src, dst, gcur, pairs, ovf, ocnt);
    bucket_csr<<<NBKT, CSR_THREADS, 0, stream>>>(gcur, pairs, ovf, ocnt,
                                                 rs, rse, col);
    wtrans_kernel<<<NL * NT, 256, 0, stream>>>(W_self, W_neigh, Wt);

    // layer dataflow: feat(f32) -> X1 bf16 (d_out) -> X2 bf16 (ws)
    //                 -> d_out f32 (final full overwrite)
    unsigned short* X1 = (unsigned short*)d_out;
    const int mgrid = (NN + 127) / 128;

    gather_kernel<0><<<GGRID, 256, 0, stream>>>(feat, rs, rse, col, meanb);
    layer_gemm<0, 1><<<mgrid, 256, 0, stream>>>(
        feat, meanb, Wt + 0 * NT * 8192, bias + 0 * NT * DD, X1, 1);
    gather_kernel<1><<<GGRID, 256, 0, stream>>>(X1, rs, rse, col, meanb);
    layer_gemm<1, 1><<<mgrid, 256, 0, stream>>>(
        X1, meanb, Wt + 1 * NT * 8192, bias + 1 * NT * DD, X2, 1);
    gather_kernel<1><<<GGRID, 256, 0, stream>>>(X2, rs, rse, col, meanb);
    layer_gemm<1, 0><<<mgrid, 256, 0, stream>>>(
        X2, meanb, Wt + 2 * NT * 8192, bias + 2 * NT * DD, d_out, 0);
}

// Round 8
// 291.354 us; speedup vs baseline: 1.1565x; 1.1565x over previous
//
#include <hip/hip_runtime.h>
#include <hip/hip_bf16.h>

// Problem constants (match reference)
#define NN 100000   // nodes
#define NE 400000   // edges per etype
#define NT 3        // etypes
#define NL 3        // layers
#define DD 64       // feature dim
#define M_TOT (NT * NN)             // 300000 concatenated (etype,node) rows
#define RPB 2048                    // rows per pair-bucket (row >> 11)
#define NBKT ((M_TOT + RPB - 1) / RPB)   // 147 buckets
#define P3CAP 64                    // LDS pairs per bucket (round-21: 512-rounds)
#define P3GRID 256                  // pair_scatter grid
#define PCAP 13312                  // fixed pair capacity per bucket
                                    //   (mean 8163 + block-drain slack 4096 + >5 sigma)
#define CSR_THREADS 1024            // bucket_csr block size (round-18)
#define COLCAP_BKT 9216             // fixed col capacity per 2048-row bucket
                                    //   (mean 8163 + ~11.7 sigma)
#define OVF_CAP 500000              // ovf region capacity (uint2 entries)

// Data established as fp32 (round-3 runtime dtype detection).
// Round-6: never fuse the random gather into the LDS-heavy GEMM (occupancy).
// Round-8: scattered 4B stores amplify ~16x at HBM -> line-grouped writes.
// Round-9: pair capacity must include per-block sentinel padding.
// Round-11: chunked (multi-edge-per-thread) pair_scatter rounds overflow
// small P3CAP; per-round per-bucket mean must stay << cap.
// Round-12/13: gather -> 8 rows/wave (ds_swizzle col broadcast, literal
// pattern): 79->46us, VALUBusy 70->22%, fetch path 2.4->3.85 TB/s. Verified.
// Round-14: gather loops to per-GROUP degree (exec-masked divergence).
// Round-15/16 LESSON (measured twice): B fragments MUST come from LDS;
// B-from-global inside the MFMA loop = latency-bound 53-56us.
// Round-17 LESSON: reg-prefetch pipeline in the LDS gemm REGRESSED; the
// compiler's own schedule beats manual loop-head prefetch. Keep r2 form.
// Round-18: bucket_csr -> ONE 1024-thread block/bucket (saved ~15us).
// Round-19/20 LESSONS (both reverted): (a) 128-row gemm tile regressed
// (+8us/dispatch; 3 blocks/CU + half the blocks lose to halved barriers);
// (b) persistent-grid gather regressed (+3us): occupancy unchanged 54% ->
// concurrency NOT the limiter; random fetch path saturated ~3.8 TB/s.
// Gather is at its structural roofline for the random-row pattern.
// Round-21 (this): pair_scatter 512-edge rounds + P3CAP=64 (37.6KB LDS):
// rounds/barriers halve, drains amortize (flush only at >=16 fill).

typedef __attribute__((ext_vector_type(8))) short bf16x8;  // 8 bf16 (4 VGPRs)
typedef __attribute__((ext_vector_type(4))) float f32x4;

static __device__ __forceinline__ unsigned short f2b(float f) {
    __hip_bfloat16 b = __float2bfloat16(f);
    return *reinterpret_cast<unsigned short*>(&b);
}
static __device__ __forceinline__ float b2f(unsigned short u) {
    __hip_bfloat16 b = *reinterpret_cast<__hip_bfloat16*>(&u);
    return __bfloat162float(b);
}

// ---- init: fixed-capacity cursors (replaces count+scan+memset+memcpy) ------
__global__ void init_kernel(int* __restrict__ gcur, int* __restrict__ ocnt) {
    int i = threadIdx.x;
    if (i < NBKT) gcur[i] = i * PCAP;
    if (i == 0) ocnt[0] = 0;
}

// ---- pair scatter: packed pairs into fixed bucket regions ------------------
// pair = (row_local<<17)|src. Global writes only as aligned 64B groups of 16;
// drain pads with sentinel 0xFFFFFFFF (src field >= NN). 512-edge rounds
// (round-21); per-round per-bucket fill mean 3.5 vs cap 64.
__global__ __launch_bounds__(256) void pair_scatter(
    const int* __restrict__ src, const int* __restrict__ dst,
    int* __restrict__ gcur, unsigned* __restrict__ pairs,
    uint2* __restrict__ ovf, int* __restrict__ ocnt) {
    __shared__ unsigned buf[NBKT][P3CAP];   // 37.6 KB
    __shared__ int fill[NBKT];
    for (int i = threadIdx.x; i < NBKT; i += 256) fill[i] = 0;
    __syncthreads();
    const int total = NT * NE;
    int per = (total + gridDim.x - 1) / gridDim.x;
    int beg = blockIdx.x * per;
    int fin = beg + per; if (fin > total) fin = total;
    for (int bse = beg; bse < fin; bse += 512) {
#pragma unroll
        for (int half = 0; half < 2; ++half) {
            int e = bse + half * 256 + threadIdx.x;
            if (e < fin) {
                int t = e / NE;
                int row = t * NN + dst[e];
                int bk = row >> 11;
                unsigned pr = ((unsigned)(row & 2047) << 17) | (unsigned)src[e];
                int pos = atomicAdd(&fill[bk], 1);
                if (pos < P3CAP) buf[bk][pos] = pr;
                else {
                    int o = atomicAdd(ocnt, 1);
                    if (o < OVF_CAP)
                        ovf[o] = make_uint2((unsigned)src[e], (unsigned)row);
                }
            }
        }
        __syncthreads();
        for (int bk = threadIdx.x; bk < NBKT; bk += 256) {
            int n = fill[bk]; if (n > P3CAP) n = P3CAP;
            int g = n >> 4;
            if (g) {
                int gb = atomicAdd(&gcur[bk], g * 16);
                for (int grp = 0; grp < g; ++grp)
#pragma unroll
                    for (int q = 0; q < 4; ++q)
                        *(int4*)&pairs[gb + grp * 16 + q * 4] =
                            *(const int4*)&buf[bk][grp * 16 + q * 4];
                int rem = n - g * 16;
                for (int k = 0; k < rem; ++k) buf[bk][k] = buf[bk][g * 16 + k];
                fill[bk] = rem;
            } else fill[bk] = n;
        }
        __syncthreads();
    }
    // drain: pad to 16 with sentinels to keep gcur 64B-aligned
    for (int bk = threadIdx.x; bk < NBKT; bk += 256) {
        int n = fill[bk]; if (n > P3CAP) n = P3CAP;
        if (n) {
            int m = (n + 15) & ~15;
            for (int k = n; k < m; ++k) buf[bk][k] = 0xFFFFFFFFu;
            int gb = atomicAdd(&gcur[bk], m);
            for (int grp = 0; grp < m >> 4; ++grp)
#pragma unroll
                for (int q = 0; q < 4; ++q)
                    *(int4*)&pairs[gb + grp * 16 + q * 4] =
                        *(const int4*)&buf[bk][grp * 16 + q * 4];
        }
    }
}

// ---- CSR finalize: ONE 1024-thread block per bucket (round-18) -------------
__global__ __launch_bounds__(CSR_THREADS) void bucket_csr(
    const int* __restrict__ gcur, const unsigned* __restrict__ pairs,
    const uint2* __restrict__ ovf, const int* __restrict__ ocnt,
    int* __restrict__ rs, int* __restrict__ rse, int* __restrict__ col) {
    __shared__ int cnt_s[RPB];
    __shared__ int cur_s[RPB];
    __shared__ int part[CSR_THREADS];
    const int bk = blockIdx.x;              // 0 .. NBKT-1
    const int row0 = bk * RPB;              // global row base
    const int nrows = (M_TOT - row0 < RPB) ? (M_TOT - row0) : RPB;
    for (int i = threadIdx.x; i < RPB; i += CSR_THREADS) cnt_s[i] = 0;
    __syncthreads();
    const int pb = bk * PCAP, pe = gcur[bk];
    for (int p = pb + threadIdx.x; p < pe; p += CSR_THREADS) {
        unsigned pr = pairs[p];
        if ((pr & 0x1FFFFu) < NN)
            atomicAdd(&cnt_s[pr >> 17], 1);   // rl < RPB by construction
    }
    int no = ocnt[0]; if (no > OVF_CAP) no = OVF_CAP;
    for (int o = threadIdx.x; o < no; o += CSR_THREADS) {
        int rl = (int)ovf[o].y - row0;
        if (rl >= 0 && rl < nrows) atomicAdd(&cnt_s[rl], 1);
    }
    __syncthreads();
    // exclusive scan of 2048 counts (2 per thread)
    int t0 = threadIdx.x * 2, sum = 0;
    int exl[2];
#pragma unroll
    for (int k = 0; k < 2; ++k) { exl[k] = sum; sum += cnt_s[t0 + k]; }
    part[threadIdx.x] = sum;
    __syncthreads();
    for (int o = 1; o < CSR_THREADS; o <<= 1) {
        int v = (threadIdx.x >= o) ? part[threadIdx.x - o] : 0;
        __syncthreads();
        part[threadIdx.x] += v;
        __syncthreads();
    }
    int off = part[threadIdx.x] - sum + bk * COLCAP_BKT;
#pragma unroll
    for (int k = 0; k < 2; ++k) {
        int idx = t0 + k;
        int ex = exl[k] + off;
        cur_s[idx] = ex;
        if (idx < nrows) { rs[row0 + idx] = ex; rse[row0 + idx] = ex + cnt_s[idx]; }
    }
    __syncthreads();
    for (int p = pb + threadIdx.x; p < pe; p += CSR_THREADS) {
        unsigned pr = pairs[p];
        unsigned s = pr & 0x1FFFFu;
        if (s < NN) {
            int pos = atomicAdd(&cur_s[pr >> 17], 1);
            col[pos] = (int)s;
        }
    }
    for (int o = threadIdx.x; o < no; o += CSR_THREADS) {
        int rl = (int)ovf[o].y - row0;
        if (rl >= 0 && rl < nrows) {
            int pos = atomicAdd(&cur_s[rl], 1);
            col[pos] = (int)ovf[o].x;
        }
    }
}

// ---- one-time weight transpose: Wt[lt][j][k] = bf16(W'[k][j]), K=128 -------
__global__ __launch_bounds__(256) void wtrans_kernel(
    const float* __restrict__ Ws, const float* __restrict__ Wn,
    unsigned short* __restrict__ Wt) {
    int lt = blockIdx.x;   // 0..8
    for (int p = threadIdx.x; p < DD * 2 * DD; p += 256) {
        int j = p >> 7, k = p & 127;
        float v = (k < DD) ? Ws[(size_t)lt * DD * DD + k * DD + j]
                           : Wn[(size_t)lt * DD * DD + (k - DD) * DD + j];
        Wt[(size_t)lt * 8192 + j * 128 + k] = f2b(v);
    }
}

// ---- aggregation: pull-mode mean gather, 8 rows per wave (r12-14) ----------
template <int HBF>
__global__ __launch_bounds__(256) void gather_kernel(
    const void* __restrict__ hv, const int* __restrict__ rs,
    const int* __restrict__ rse, const int* __restrict__ col,
    unsigned short* __restrict__ meanb) {
    const int lane = threadIdx.x & 63;
    const int g = lane >> 3;       // row group within wave (0..7)
    const int fc = lane & 7;       // feature chunk (8 feats x 16B)
    const int i = (blockIdx.x * 4 + (threadIdx.x >> 6)) * 8 + g;
    const bool live = i < M_TOT;   // grid is exact; kept for safety
    const int start = live ? rs[i] : 0;
    const int end   = live ? rse[i] : 0;
    const int deg = end - start;   // uniform within the 8-lane group
    float acc[8];
#pragma unroll
    for (int j = 0; j < 8; ++j) acc[j] = 0.f;
    const unsigned short* hb = (const unsigned short*)hv;
    const float* hf = (const float*)hv;
    for (int base = 0; base < deg; base += 8) {
        int e = start + base + fc;
        int cl = col[(e < end) ? e : start];   // 8 contiguous cols per group

#define GSTEP(K)                                                               \
        {                                                                      \
            int idx = __builtin_amdgcn_ds_swizzle(cl, ((K) << 5) | 24);        \
            bool v = (base + (K)) < deg;                                       \
            float mk = v ? 1.f : 0.f;                                          \
            int ix = v ? idx : 0;                                              \
            if (HBF) {                                                         \
                int4 rv = *(const int4*)&hb[(size_t)ix * DD + fc * 8];         \
                const unsigned* wp = (const unsigned*)&rv;                     \
                _Pragma("unroll")                                              \
                for (int j = 0; j < 4; ++j) {                                  \
                    unsigned w = wp[j];                                        \
                    float lo = __uint_as_float(w << 16);                       \
                    float hi = __uint_as_float(w & 0xffff0000u);               \
                    acc[2 * j]     = fmaf(lo, mk, acc[2 * j]);                 \
                    acc[2 * j + 1] = fmaf(hi, mk, acc[2 * j + 1]);             \
                }                                                              \
            } else {                                                           \
                float4 a = *(const float4*)&hf[(size_t)ix * DD + fc * 8];      \
                float4 b = *(const float4*)&hf[(size_t)ix * DD + fc * 8 + 4];  \
                acc[0] = fmaf(a.x, mk, acc[0]);                                \
                acc[1] = fmaf(a.y, mk, acc[1]);                                \
                acc[2] = fmaf(a.z, mk, acc[2]);                                \
                acc[3] = fmaf(a.w, mk, acc[3]);                                \
                acc[4] = fmaf(b.x, mk, acc[4]);                                \
                acc[5] = fmaf(b.y, mk, acc[5]);                                \
                acc[6] = fmaf(b.z, mk, acc[6]);                                \
                acc[7] = fmaf(b.w, mk, acc[7]);                                \
            }                                                                  \
        }
        GSTEP(0) GSTEP(1) GSTEP(2) GSTEP(3)
        GSTEP(4) GSTEP(5) GSTEP(6) GSTEP(7)
#undef GSTEP
    }
    float sc = (deg > 0) ? 1.f / (float)deg : 0.f;
    unsigned ow[4];
#pragma unroll
    for (int j = 0; j < 4; ++j) {
        unsigned lo = f2b(acc[2 * j] * sc);
        unsigned hi = f2b(acc[2 * j + 1] * sc);
        ow[j] = lo | (hi << 16);
    }
    if (live)
        *(int4*)&meanb[(size_t)i * DD + fc * 8] = *(const int4*)ow;
}

// ---- per-layer fused MFMA GEMM over all 3 etypes (r2-proven form) ----------
template <int HBF, int OBF>
__global__ __launch_bounds__(256) void layer_gemm(
    const void* __restrict__ hv, const unsigned short* __restrict__ meanb,
    const unsigned short* __restrict__ Wt, const float* __restrict__ bias,
    void* __restrict__ outv, int relu) {
    __shared__ __align__(16) short A_s[64 * 136];  // [row][k]: k<64 h, k>=64 mean
    __shared__ __align__(16) short B_s[64 * 136];  // [col j][k]

    const int tx = threadIdx.x;
    const int n0 = blockIdx.x * 64;
    const int lane = tx & 63, w = tx >> 6;
    const int q = lane >> 4, m16 = lane & 15;
    const int rr = tx >> 4;
    const int k0 = (tx & 15) * 4;
    const int bj = tx >> 2;
    const int bk = (tx & 3) * 32;

#pragma unroll
    for (int qq = 0; qq < 4; ++qq) {
        int r = rr + 16 * qq;
        int n = n0 + r;
        ushort4 hb4 = make_ushort4(0, 0, 0, 0);
        if (n < NN) {
            if (HBF) {
                hb4 = *(const ushort4*)&((const unsigned short*)hv)[(size_t)n * DD + k0];
            } else {
                float4 hf = *(const float4*)&((const float*)hv)[(size_t)n * DD + k0];
                hb4 = make_ushort4(f2b(hf.x), f2b(hf.y), f2b(hf.z), f2b(hf.w));
            }
        }
        *(ushort4*)&A_s[r * 136 + k0] = hb4;
    }

    float acc_sum[4][4];
#pragma unroll
    for (int c = 0; c < 4; ++c)
#pragma unroll
        for (int r = 0; r < 4; ++r) acc_sum[c][r] = 0.f;

    for (int t = 0; t < NT; ++t) {
#pragma unroll
        for (int qq = 0; qq < 4; ++qq) {
            int r = rr + 16 * qq;
            int n = n0 + r;
            ushort4 mv = make_ushort4(0, 0, 0, 0);
            if (n < NN)
                mv = *(const ushort4*)&meanb[((size_t)t * NN + n) * DD + k0];
            *(ushort4*)&A_s[r * 136 + 64 + k0] = mv;
        }
        {
            const unsigned short* wt = Wt + (size_t)t * 8192 + bj * 128 + bk;
#pragma unroll
            for (int u = 0; u < 4; ++u)
                *(int4*)&B_s[bj * 136 + bk + u * 8] = *(const int4*)&wt[u * 8];
        }
        __syncthreads();

        f32x4 acc[4];
#pragma unroll
        for (int c = 0; c < 4; ++c) acc[c] = (f32x4){0.f, 0.f, 0.f, 0.f};
#pragma unroll
        for (int kt = 0; kt < 4; ++kt) {
            bf16x8 a = *(const bf16x8*)&A_s[(16 * w + m16) * 136 + kt * 32 + q * 8];
#pragma unroll
            for (int c = 0; c < 4; ++c) {
                bf16x8 b = *(const bf16x8*)&B_s[(c * 16 + m16) * 136 + kt * 32 + q * 8];
                acc[c] = __builtin_amdgcn_mfma_f32_16x16x32_bf16(a, b, acc[c], 0, 0, 0);
            }
        }

#pragma unroll
        for (int c = 0; c < 4; ++c) {
            float bv = bias[t * DD + c * 16 + m16];
#pragma unroll
            for (int r = 0; r < 4; ++r) {
                float v = acc[c][r] + bv;
                if (relu) v = fmaxf(v, 0.f);
                acc_sum[c][r] += v;
            }
        }
        __syncthreads();
    }

#pragma unroll
    for (int c = 0; c < 4; ++c)
#pragma unroll
        for (int r = 0; r < 4; ++r) {
            int n = n0 + 16 * w + q * 4 + r;
            if (n >= NN) continue;
            size_t idx = (size_t)n * DD + c * 16 + m16;
            if (OBF)
                ((unsigned short*)outv)[idx] = f2b(acc_sum[c][r]);
            else
                ((float*)outv)[idx] = acc_sum[c][r];
        }
}

extern "C" void kernel_launch(void* const* d_in, const int* in_sizes, int n_in,
                              void* d_out, int out_size, void* d_ws, size_t ws_size,
                              hipStream_t stream) {
    const float* feat    = (const float*)d_in[0];
    const float* W_self  = (const float*)d_in[1];
    const float* W_neigh = (const float*)d_in[2];
    const float* bias    = (const float*)d_in[3];
    const int* src = (const int*)d_in[4];
    const int* dst = (const int*)d_in[5];

    // ws layout (byte offsets; total 59.18 MB <= proven 59.6 MB):
    //   gcur @0 (1 KB) | ocnt @1024 | rs @8192 (1.2 MB) | rse @1,208,320
    //   col @2,408,448 (5.42 MB: 147 x 9216 ints)
    //   Wt  @7,827,584 (147,456 B)
    //   X2  @7,975,040 (12.8 MB bf16)
    //   meanb @20,775,040 (38.4 MB bf16)
    //   pairs = alias of meanb (7.83 MB: 147 x 13312, dead after bucket_csr)
    //   ovf   = meanb + 8,388,608 (4 MB, dead after bucket_csr)
    char* ws = (char*)d_ws;
    int* gcur  = (int*)(ws + 0);
    int* ocnt  = (int*)(ws + 1024);
    int* rs    = (int*)(ws + 8192);
    int* rse   = (int*)(ws + 1208320);
    int* col   = (int*)(ws + 2408448);
    unsigned short* Wt    = (unsigned short*)(ws + 7827584);
    unsigned short* X2    = (unsigned short*)(ws + 7975040);
    unsigned short* meanb = (unsigned short*)(ws + 20775040);
    unsigned*       pairs = (unsigned*)(ws + 20775040);
    uint2*          ovf   = (uint2*)(ws + 20775040 + 8388608);

    // ---- CSR build: fixed-capacity buckets, no count/scan pass ----
    init_kernel<<<1, 256, 0, stream>>>(gcur, ocnt);
    pair_scatter<<<P3GRID, 256, 0, stream>>>(src, dst, gcur, pairs, ovf, ocnt);
    bucket_csr<<<NBKT, CSR_THREADS, 0, stream>>>(gcur, pairs, ovf, ocnt,
                                                 rs, rse, col);
    wtrans_kernel<<<NL * NT, 256, 0, stream>>>(W_self, W_neigh, Wt);

    // layer dataflow: feat(f32) -> X1 bf16 (d_out) -> X2 bf16 (ws)
    //                 -> d_out f32 (final full overwrite)
    unsigned short* X1 = (unsigned short*)d_out;
    const int ggrid = (M_TOT + 31) / 32;   // 8 rows/wave x 4 waves = 32 rows/block
    const int mgrid = (NN + 63) / 64;

    gather_kernel<0><<<ggrid, 256, 0, stream>>>(feat, rs, rse, col, meanb);
    layer_gemm<0, 1><<<mgrid, 256, 0, stream>>>(
        feat, meanb, Wt + 0 * NT * 8192, bias + 0 * NT * DD, X1, 1);
    gather_kernel<1><<<ggrid, 256, 0, stream>>>(X1, rs, rse, col, meanb);
    layer_gemm<1, 1><<<mgrid, 256, 0, stream>>>(
        X1, meanb, Wt + 1 * NT * 8192, bias + 1 * NT * DD, X2, 1);
    gather_kernel<1><<<ggrid, 256, 0, stream>>>(X2, rs, rse, col, meanb);
    layer_gemm<1, 0><<<mgrid, 256, 0, stream>>>(
        X2, meanb, Wt + 2 * NT * 8192, bias + 2 * NT * DD, d_out, 0);
}